// Round 7
// baseline (1509.412 us; speedup 1.0000x reference)
//
#include <hip/hip_runtime.h>
#include <hip/hip_bf16.h>

// Problem constants
#define B_    16
#define T_    1000
#define FEAT  771
#define FEATP 776      // 771 padded to multiple of 8 (16B-aligned fp16 rows)
#define H_    512
#define H3    1536
#define KN_   9
#define KHID  4608     // H*KN
#define M_    16000    // B*T
#define NOUT  257      // output column slice [257:514)
#define KSLICES 3      // split-K factor for the final GEMM
#define SDEPTH 10      // scan prefetch ring depth (1000 = 100*10)

typedef _Float16 half8 __attribute__((ext_vector_type(8)));
typedef _Float16 half4 __attribute__((ext_vector_type(4)));
typedef _Float16 half2v __attribute__((ext_vector_type(2)));
typedef float    floatx4 __attribute__((ext_vector_type(4)));

__device__ inline half8 h8zero() {
    half8 v;
    #pragma unroll
    for (int i = 0; i < 8; ++i) v[i] = (_Float16)0.f;
    return v;
}

// tanh(z) = 1 - 2/(1+e^{2z})  — saturates correctly at +/-inf, no NaN
__device__ inline float tanh_fast(float z) {
    return 1.0f - 2.0f / (1.0f + __expf(2.0f * z));
}
__device__ inline float sigmoid_fast(float z) {
    return 1.0f / (1.0f + __expf(-z));
}

// ---------------------------------------------------------------------------
// fp32 -> fp16 convert of inputs, padding rows 771 -> 776 with zeros
__global__ void convert_inputs(const float* __restrict__ in, _Float16* __restrict__ A1) {
    size_t i = (size_t)blockIdx.x * 256 + threadIdx.x;
    if (i >= (size_t)M_ * FEATP) return;
    size_t r = i / FEATP;
    int   cc = (int)(i % FEATP);
    A1[i] = (cc < FEAT) ? (_Float16)in[r * FEAT + cc] : (_Float16)0.f;
}

// ---------------------------------------------------------------------------
// LDS-tiled transpose+convert: Wt[n*Kp + k] = (k<K) ? W[k*ldw + coloff + n] : 0
__global__ __launch_bounds__(256) void transpose_w(
    const float* __restrict__ W, _Float16* __restrict__ Wt,
    int K, int N, int ldw, int coloff, int Kp)
{
    __shared__ float tile[32][33];
    const int kb = blockIdx.x * 32;
    const int nb = blockIdx.y * 32;
    const int tx = threadIdx.x & 31;
    const int ty = threadIdx.x >> 5;   // 0..7
    #pragma unroll
    for (int r = ty; r < 32; r += 8) {
        const int k = kb + r, n = nb + tx;
        tile[r][tx] = (k < K && n < N) ? W[(size_t)k * ldw + coloff + n] : 0.f;
    }
    __syncthreads();
    #pragma unroll
    for (int r = ty; r < 32; r += 8) {
        const int n = nb + r, k = kb + tx;
        if (n < N && k < Kp) Wt[(size_t)n * Kp + k] = (_Float16)tile[tx][r];
    }
}

// ---------------------------------------------------------------------------
// Tiled fp16 MFMA GEMM: C[M x N] = A[M x Kp] * Bt[N x Kp]^T, fp32 accumulate.
// 128x128 block tile, BK=32, 4 waves (2x2), each wave 4x4 of 16x16x32 MFMA.
// blockIdx.z selects a K-slice of nk BK-iterations (split-K; z=0 when gridDim.z==1).
// EPI 0: tanh(+bias) -> dense fp16 Ch[row*ldc+col]
// EPI 1: raw -> SoA U planes: Ch[(col>>9)*M*512 + row*512 + (col&511)]
// EPI 3: raw fp32 partial -> Cf[z*M*NOUT + row*NOUT + col]   (split-K partial)
template <int EPI>
__global__ __launch_bounds__(256) void gemm_kernel(
    const _Float16* __restrict__ A, const _Float16* __restrict__ Bt,
    int Kp, int nk, int Nb,
    _Float16* __restrict__ Ch, float* __restrict__ Cf, int ldc,
    const float* __restrict__ bias)
{
    __shared__ __align__(16) _Float16 As[128][40];  // +8 pad, 16B-aligned rows
    __shared__ __align__(16) _Float16 Bs[128][40];

    const int tid  = threadIdx.x;
    const int m0   = blockIdx.x * 128;
    const int n0   = blockIdx.y * 128;
    const int koff = blockIdx.z * (nk << 5);   // K-slice origin
    const int wave = tid >> 6;
    const int lane = tid & 63;
    const int wr   = (wave >> 1) << 6;   // wave row offset (0/64)
    const int wc   = (wave & 1) << 6;    // wave col offset (0/64)
    const int lrow = lane & 15;
    const int lq   = lane >> 4;          // 0..3
    const int srow = tid >> 1;           // staging row 0..127
    const int scol = (tid & 1) << 4;     // staging col 0 or 16

    floatx4 acc[4][4];
    #pragma unroll
    for (int i = 0; i < 4; ++i)
        #pragma unroll
        for (int j = 0; j < 4; ++j)
            #pragma unroll
            for (int r = 0; r < 4; ++r) acc[i][j][r] = 0.f;

    const _Float16* aRow = A + (size_t)(m0 + srow) * Kp + koff;
    const int  brow   = n0 + srow;
    const _Float16* bRow = Bt + (size_t)brow * Kp + koff;
    const bool bvalid = (brow < Nb);

    for (int kc = 0; kc < nk; ++kc) {
        const int k0 = kc << 5;
        __syncthreads();
        #pragma unroll
        for (int s = 0; s < 2; ++s) {
            const int kk = k0 + scol + s * 8;
            half8 va = h8zero(), vb = h8zero();
            const bool kin = (koff + kk + 8 <= Kp);
            if (kin)           va = *(const half8*)(aRow + kk);
            if (kin && bvalid) vb = *(const half8*)(bRow + kk);
            *(half8*)(&As[srow][scol + s * 8]) = va;
            *(half8*)(&Bs[srow][scol + s * 8]) = vb;
        }
        __syncthreads();

        half8 af[4], bfr[4];
        #pragma unroll
        for (int i = 0; i < 4; ++i) af[i]  = *(const half8*)(&As[wr + i * 16 + lrow][lq * 8]);
        #pragma unroll
        for (int j = 0; j < 4; ++j) bfr[j] = *(const half8*)(&Bs[wc + j * 16 + lrow][lq * 8]);
        #pragma unroll
        for (int i = 0; i < 4; ++i)
            #pragma unroll
            for (int j = 0; j < 4; ++j)
                acc[i][j] = __builtin_amdgcn_mfma_f32_16x16x32_f16(af[i], bfr[j], acc[i][j], 0, 0, 0);
    }

    // Epilogue: C/D layout col=lane&15, row=quad*4+reg
    #pragma unroll
    for (int j = 0; j < 4; ++j) {
        const int col = n0 + wc + j * 16 + lrow;
        if (col >= Nb) continue;
        #pragma unroll
        for (int i = 0; i < 4; ++i) {
            #pragma unroll
            for (int r = 0; r < 4; ++r) {
                const int row = m0 + wr + i * 16 + lq * 4 + r;
                float v = acc[i][j][r];
                if constexpr (EPI == 0) {
                    float z = v + bias[col];
                    Ch[(size_t)row * ldc + col] = (_Float16)tanh_fast(z);
                } else if constexpr (EPI == 1) {
                    Ch[(size_t)(col >> 9) * ((size_t)M_ * 512) + (size_t)row * 512 + (col & 511)] = (_Float16)v;
                } else {
                    Cf[(size_t)blockIdx.z * M_ * NOUT + (size_t)row * NOUT + col] = v;
                }
            }
        }
    }
}

// ---------------------------------------------------------------------------
// Split-K reduction + sigmoid epilogue for the final GEMM.
__global__ __launch_bounds__(256) void reduce_out(
    const float* __restrict__ Cp, const float* __restrict__ bias,
    const float* __restrict__ aux, float* __restrict__ out)
{
    const size_t i = (size_t)blockIdx.x * 256 + threadIdx.x;
    if (i >= (size_t)M_ * NOUT) return;
    const int row = (int)(i / NOUT);
    const int col = (int)(i % NOUT);
    float s = Cp[i] + Cp[i + (size_t)M_ * NOUT] + Cp[i + 2 * (size_t)M_ * NOUT];
    out[i] = sigmoid_fast(s + bias[col]) * aux[(size_t)row * FEAT + 257 + col];
}

// ---------------------------------------------------------------------------
// SRU scan over SoA U planes: U0/U1/U2 = xt/fp/rp, each [M][512] fp16 dense;
// x read from the dense previous-layer activations Xin [M][512].
// Every per-step load is 64 lanes x 2 B contiguous = one 128-B transaction.
// Depth-SDEPTH register ring per stream (4*SDEPTH outstanding loads) covers
// the load latency; 1000 = 100 * SDEPTH, no tail.
__global__ __launch_bounds__(64) void sru_scan(
    const _Float16* __restrict__ U, const _Float16* __restrict__ Xin,
    _Float16* __restrict__ Xout,
    const float* __restrict__ v, const float* __restrict__ bg)
{
    const int gid = blockIdx.x * 64 + threadIdx.x;
    const int b = gid >> 9;
    const int h = gid & 511;
    const float vf = v[h],      vr = v[512 + h];
    const float bf = bg[h],     br = bg[512 + h];

    const size_t chain = (size_t)b * T_ * 512 + h;
    const _Float16* p0 = U + chain;                       // xt plane
    const _Float16* p1 = U + (size_t)M_ * 512 + chain;    // fp plane
    const _Float16* p2 = U + 2 * (size_t)M_ * 512 + chain;// rp plane
    const _Float16* px = Xin + chain;
    _Float16*       ox = Xout + chain;

    _Float16 b0[SDEPTH], b1[SDEPTH], b2[SDEPTH], b3[SDEPTH];
    #pragma unroll
    for (int j = 0; j < SDEPTH; ++j) {
        const size_t o = (size_t)j * 512;
        b0[j] = p0[o]; b1[j] = p1[o]; b2[j] = p2[o]; b3[j] = px[o];
    }

    float c = 0.f;
    for (int t0 = 0; t0 < T_; t0 += SDEPTH) {
        #pragma unroll
        for (int j = 0; j < SDEPTH; ++j) {
            const int t = t0 + j;
            const float xt = (float)b0[j];
            const float fp = (float)b1[j];
            const float rp = (float)b2[j];
            const float x  = (float)b3[j];
            const int tn = t + SDEPTH;
            if (tn < T_) {
                const size_t o = (size_t)tn * 512;
                b0[j] = p0[o]; b1[j] = p1[o]; b2[j] = p2[o]; b3[j] = px[o];
            }
            const float f  = sigmoid_fast(fp + vf * c + bf);
            const float r  = sigmoid_fast(rp + vr * c + br);
            const float cn = f * c + (1.0f - f) * xt;
            const float hO = r * cn + (1.0f - r) * x;
            ox[(size_t)t * 512] = (_Float16)hO;
            c = cn;
        }
    }
}

// ---------------------------------------------------------------------------
// Fused conv6x6(asym pad 3,2) + bias + tanh + maxpool3x3(pad 1).
// Weights are read with wave-uniform indices directly from global -> scalar
// loads into SGPRs (zero LDS weight traffic). cv kept in fp16 to halve LDS.
// Row loop rolled to bound register pressure (no scratch).
template <int JJ>
__device__ inline floatx4 window4(floatx4 a, floatx4 b, float r8) {
    floatx4 w;
    if constexpr (JJ == 0)      { w = a; }
    else if constexpr (JJ == 1) { w[0] = a[1]; w[1] = a[2]; w[2] = a[3]; w[3] = b[0]; }
    else if constexpr (JJ == 2) { w[0] = a[2]; w[1] = a[3]; w[2] = b[0]; w[3] = b[1]; }
    else if constexpr (JJ == 3) { w[0] = a[3]; w[1] = b[0]; w[2] = b[1]; w[3] = b[2]; }
    else if constexpr (JJ == 4) { w = b; }
    else                        { w[0] = b[1]; w[1] = b[2]; w[2] = b[3]; w[3] = r8; }
    return w;
}

#define CVW 76   // cv row width (halves)

__global__ __launch_bounds__(320) void conv_pool(
    const _Float16* __restrict__ X, const float* __restrict__ ck,
    const float* __restrict__ cb, _Float16* __restrict__ A3)
{
    __shared__ __align__(16) float    in_s[23][76];       // t0-4..t0+18, h0-4..h0+71 (fp32)
    __shared__ __align__(16) _Float16 cv[9][18][CVW];     // tanh(conv) fp16; -65504 = outside
    const int tid = threadIdx.x;
    int bi = blockIdx.x;
    const int th = bi & 7;  bi >>= 3;
    const int tt = bi % 63;
    const int b  = bi / 63;
    const int t0 = tt * 16, h0 = th * 64;

    for (int i = tid; i < 23 * 76; i += 320) {
        const int r = i / 76, cc = i % 76;
        const int gt = t0 - 4 + r, gh = h0 - 4 + cc;
        float val = 0.f;   // conv zero-padding
        if (gt >= 0 && gt < T_ && gh >= 0 && gh < H_)
            val = (float)X[((size_t)b * T_ + gt) * H_ + gh];
        in_s[r][cc] = val;
    }
    __syncthreads();

    // conv phase: 18 pt x 17 ph-groups = 306 tasks, one per thread
    if (tid < 306) {
        const int pt = tid / 17;        // conv row: ct = t0 - 1 + pt
        const int co = (tid % 17) * 4;  // conv col offset: ch = h0 - 1 + co + q
        const float* inb = &in_s[pt][co];

        const int ct = t0 - 1 + pt;
        const bool rok = (ct >= 0) && (ct < T_);
        const int chb = h0 - 1 + co;
        const bool ok0 = rok && (chb + 0 >= 0) && (chb + 0 < H_);
        const bool ok1 = rok && (chb + 1 >= 0) && (chb + 1 < H_);
        const bool ok2 = rok && (chb + 2 >= 0) && (chb + 2 < H_);
        const bool ok3 = rok && (chb + 3 >= 0) && (chb + 3 < H_);

        #define EMIT_K(K, VV)                                                  \
        {                                                                      \
            const floatx4 vz = (VV);                                           \
            const float bk = cb[K];                                            \
            half4 o;                                                           \
            o[0] = ok0 ? (_Float16)tanh_fast(vz[0] + bk) : (_Float16)(-65504.f); \
            o[1] = ok1 ? (_Float16)tanh_fast(vz[1] + bk) : (_Float16)(-65504.f); \
            o[2] = ok2 ? (_Float16)tanh_fast(vz[2] + bk) : (_Float16)(-65504.f); \
            o[3] = ok3 ? (_Float16)tanh_fast(vz[3] + bk) : (_Float16)(-65504.f); \
            *(half4*)(&cv[K][pt][co]) = o;                                     \
        }

        {   // pass 0: kernels 0..4 (weights via uniform scalar loads)
            floatx4 c0 = 0.f, c1 = 0.f, c2 = 0.f, c3 = 0.f, c4 = 0.f;
            #pragma unroll 1
            for (int ii = 0; ii < 6; ++ii) {
                const float* row = inb + ii * 76;
                const floatx4 ra = *(const floatx4*)(row);
                const floatx4 rb = *(const floatx4*)(row + 4);
                const float   r8 = row[8];
                const float* wt = ck + ii * 6;   // + k*36 + jj, wave-uniform
                #define TAP0(J)                                                \
                {                                                              \
                    const floatx4 win = window4<J>(ra, rb, r8);                \
                    c0 += wt[0 * 36 + (J)] * win;                              \
                    c1 += wt[1 * 36 + (J)] * win;                              \
                    c2 += wt[2 * 36 + (J)] * win;                              \
                    c3 += wt[3 * 36 + (J)] * win;                              \
                    c4 += wt[4 * 36 + (J)] * win;                              \
                }
                TAP0(0) TAP0(1) TAP0(2) TAP0(3) TAP0(4) TAP0(5)
                #undef TAP0
            }
            EMIT_K(0, c0) EMIT_K(1, c1) EMIT_K(2, c2) EMIT_K(3, c3) EMIT_K(4, c4)
        }
        {   // pass 1: kernels 5..8
            floatx4 c0 = 0.f, c1 = 0.f, c2 = 0.f, c3 = 0.f;
            #pragma unroll 1
            for (int ii = 0; ii < 6; ++ii) {
                const float* row = inb + ii * 76;
                const floatx4 ra = *(const floatx4*)(row);
                const floatx4 rb = *(const floatx4*)(row + 4);
                const float   r8 = row[8];
                const float* wt = ck + 5 * 36 + ii * 6;
                #define TAP1(J)                                                \
                {                                                              \
                    const floatx4 win = window4<J>(ra, rb, r8);                \
                    c0 += wt[0 * 36 + (J)] * win;                              \
                    c1 += wt[1 * 36 + (J)] * win;                              \
                    c2 += wt[2 * 36 + (J)] * win;                              \
                    c3 += wt[3 * 36 + (J)] * win;                              \
                }
                TAP1(0) TAP1(1) TAP1(2) TAP1(3) TAP1(4) TAP1(5)
                #undef TAP1
            }
            EMIT_K(5, c0) EMIT_K(6, c1) EMIT_K(7, c2) EMIT_K(8, c3)
        }
        #undef EMIT_K
    }
    __syncthreads();

    // pool phase: 16 pt x 16 ph-groups of 4 = 256 tasks
    if (tid < 256) {
        const int pt = tid >> 4;
        const int gt = t0 + pt;
        if (gt < T_) {
            const int ph = (tid & 15) * 4;
            _Float16* dst = A3 + ((size_t)b * T_ + gt) * KHID + (size_t)(h0 + ph) * KN_;
            #pragma unroll
            for (int k = 0; k < 9; ++k) {
                float q0 = -1e30f, q1 = -1e30f, q2 = -1e30f, q3 = -1e30f;
                #pragma unroll
                for (int dr = 0; dr < 3; ++dr) {
                    const _Float16* cr = &cv[k][pt + dr][ph];
                    const half4  a = *(const half4*)(cr);
                    const half2v bq = *(const half2v*)(cr + 4);
                    const float v0 = (float)a[0], v1 = (float)a[1], v2 = (float)a[2];
                    const float v3 = (float)a[3], v4 = (float)bq[0], v5 = (float)bq[1];
                    const float t01 = fmaxf(v1, v2);
                    const float t34 = fmaxf(v3, v4);
                    q0 = fmaxf(q0, fmaxf(v0, t01));
                    q1 = fmaxf(q1, fmaxf(t01, v3));
                    q2 = fmaxf(q2, fmaxf(v2, t34));
                    q3 = fmaxf(q3, fmaxf(t34, v5));
                }
                dst[0 * KN_ + k] = (_Float16)q0;
                dst[1 * KN_ + k] = (_Float16)q1;
                dst[2 * KN_ + k] = (_Float16)q2;
                dst[3 * KN_ + k] = (_Float16)q3;
            }
        }
    }
}

// ---------------------------------------------------------------------------
extern "C" void kernel_launch(void* const* d_in, const int* in_sizes, int n_in,
                              void* d_out, int out_size, void* d_ws, size_t ws_size,
                              hipStream_t stream) {
    const float* inputs = (const float*)d_in[0];
    const float* W_in   = (const float*)d_in[1];
    const float* b_in   = (const float*)d_in[2];
    const float* W_rnn  = (const float*)d_in[3];
    const float* v_rnn  = (const float*)d_in[4];
    const float* b_rnn  = (const float*)d_in[5];
    const float* conv_k = (const float*)d_in[6];
    const float* conv_b = (const float*)d_in[7];
    const float* W_out  = (const float*)d_in[8];
    const float* b_out  = (const float*)d_in[9];
    float* out = (float*)d_out;

    char* ws = (char*)d_ws;
    size_t off = 0;
    auto take = [&](size_t bytes) -> char* {
        off = (off + 255) & ~(size_t)255;
        char* p = ws + off;
        off += bytes;
        return p;
    };
    // W3T first so it survives; A1..X1 form a dead span at G3 time for Cp alias.
    _Float16* W3T  = (_Float16*)take((size_t)NOUT * KHID * 2);  // W_out[:,257:514]^T (live at G3)
    _Float16* A1   = (_Float16*)take((size_t)M_ * FEATP * 2);   // inputs fp16, padded (dead after G1)
    _Float16* W1T  = (_Float16*)take((size_t)H_ * FEATP * 2);   // W_in^T
    _Float16* W2T0 = (_Float16*)take((size_t)H3 * H_ * 2);      // W_rnn[0]^T
    _Float16* W2T1 = (_Float16*)take((size_t)H3 * H_ * 2);      // W_rnn[1]^T
    _Float16* X0   = (_Float16*)take((size_t)M_ * H_ * 2);      // tanh(G1); dead after scan0
    _Float16* X1   = (_Float16*)take((size_t)M_ * H_ * 2);      // scan0 out; dead after scan1
    _Float16* U    = (_Float16*)take(3 * (size_t)M_ * 512 * 2); // SoA U planes (xt,fp,rp), reused per layer
    _Float16* A3   = (_Float16*)take((size_t)M_ * KHID * 2);    // pooled conv, (h*9+k) layout
    // Split-K partials alias the dead A1..X1 span (KSLICES*M*NOUT*4 = 49.4 MB < 61.6 MB span):
    float* Cp = (float*)A1;
    _Float16* X2 = X0;  // X0 dead after scan0 -> reuse for scan1 output

    // --- weight/input preprocessing (fp32 -> fp16, transpose to NxK) ---
    {
        size_t n = (size_t)M_ * FEATP;
        convert_inputs<<<dim3((unsigned)((n + 255) / 256)), 256, 0, stream>>>(inputs, A1);
    }
    transpose_w<<<dim3(25, 16), 256, 0, stream>>>(W_in, W1T, FEAT, H_, H_, 0, FEATP);
    transpose_w<<<dim3(16, 48), 256, 0, stream>>>(W_rnn, W2T0, H_, H3, H3, 0, H_);
    transpose_w<<<dim3(16, 48), 256, 0, stream>>>(W_rnn + (size_t)H_ * H3, W2T1, H_, H3, H3, 0, H_);
    transpose_w<<<dim3(144, 9), 256, 0, stream>>>(W_out, W3T, KHID, NOUT, FEAT, 257, KHID);

    // --- G1: X0 = tanh(inputs @ W_in + b_in) ---
    gemm_kernel<0><<<dim3(125, 4), 256, 0, stream>>>(A1, W1T, FEATP, 25, H_, X0, nullptr, H_, b_in);

    // --- SRU layer 0 ---
    gemm_kernel<1><<<dim3(125, 12), 256, 0, stream>>>(X0, W2T0, H_, 16, H3, U, nullptr, 0, nullptr);
    sru_scan<<<dim3(128), 64, 0, stream>>>(U, X0, X1, v_rnn, b_rnn);

    // --- SRU layer 1 ---
    gemm_kernel<1><<<dim3(125, 12), 256, 0, stream>>>(X1, W2T1, H_, 16, H3, U, nullptr, 0, nullptr);
    sru_scan<<<dim3(128), 64, 0, stream>>>(U, X1, X2, v_rnn + 1024, b_rnn + 1024);

    // --- conv + tanh + maxpool fused, producing final-GEMM A matrix ---
    conv_pool<<<dim3(16 * 63 * 8), 320, 0, stream>>>(X2, conv_k, conv_b, A3);

    // --- G3 split-K: Cp[z] = A3 @ W3T (K-slice z), then reduce+sigmoid+mask ---
    gemm_kernel<3><<<dim3(125, 3, KSLICES), 256, 0, stream>>>(A3, W3T, KHID, 144 / KSLICES, NOUT, nullptr, Cp, 0, nullptr);
    {
        const unsigned nred = (unsigned)(((size_t)M_ * NOUT + 255) / 256);
        reduce_out<<<dim3(nred), 256, 0, stream>>>(Cp, b_out + 257, inputs, out);
    }
}

// Round 8
// 916.698 us; speedup vs baseline: 1.6466x; 1.6466x over previous
//
#include <hip/hip_runtime.h>
#include <hip/hip_bf16.h>

// Problem constants
#define B_    16
#define T_    1000
#define FEAT  771
#define FEATP 776      // 771 padded to multiple of 8 (16B-aligned fp16 rows)
#define H_    512
#define H3    1536
#define KN_   9
#define KHID  4608     // H*KN
#define M_    16000    // B*T
#define NOUT  257      // output column slice [257:514)
#define KSLICES 3      // split-K factor for the final GEMM

typedef _Float16 half8 __attribute__((ext_vector_type(8)));
typedef _Float16 half4 __attribute__((ext_vector_type(4)));
typedef _Float16 half2v __attribute__((ext_vector_type(2)));
typedef float    floatx4 __attribute__((ext_vector_type(4)));

__device__ inline half8 h8zero() {
    half8 v;
    #pragma unroll
    for (int i = 0; i < 8; ++i) v[i] = (_Float16)0.f;
    return v;
}

// tanh(z) = 1 - 2/(1+e^{2z})  — saturates correctly at +/-inf, no NaN
__device__ inline float tanh_fast(float z) {
    return 1.0f - 2.0f / (1.0f + __expf(2.0f * z));
}
__device__ inline float sigmoid_fast(float z) {
    return 1.0f / (1.0f + __expf(-z));
}

// ---------------------------------------------------------------------------
// fp32 -> fp16 convert of inputs, padding rows 771 -> 776 with zeros
__global__ void convert_inputs(const float* __restrict__ in, _Float16* __restrict__ A1) {
    size_t i = (size_t)blockIdx.x * 256 + threadIdx.x;
    if (i >= (size_t)M_ * FEATP) return;
    size_t r = i / FEATP;
    int   cc = (int)(i % FEATP);
    A1[i] = (cc < FEAT) ? (_Float16)in[r * FEAT + cc] : (_Float16)0.f;
}

// ---------------------------------------------------------------------------
// LDS-tiled transpose+convert: Wt[n*Kp + k] = (k<K) ? W[k*ldw + coloff + n] : 0
__global__ __launch_bounds__(256) void transpose_w(
    const float* __restrict__ W, _Float16* __restrict__ Wt,
    int K, int N, int ldw, int coloff, int Kp)
{
    __shared__ float tile[32][33];
    const int kb = blockIdx.x * 32;
    const int nb = blockIdx.y * 32;
    const int tx = threadIdx.x & 31;
    const int ty = threadIdx.x >> 5;   // 0..7
    #pragma unroll
    for (int r = ty; r < 32; r += 8) {
        const int k = kb + r, n = nb + tx;
        tile[r][tx] = (k < K && n < N) ? W[(size_t)k * ldw + coloff + n] : 0.f;
    }
    __syncthreads();
    #pragma unroll
    for (int r = ty; r < 32; r += 8) {
        const int n = nb + r, k = kb + tx;
        if (n < N && k < Kp) Wt[(size_t)n * Kp + k] = (_Float16)tile[tx][r];
    }
}

// ---------------------------------------------------------------------------
// Tiled fp16 MFMA GEMM: C[M x N] = A[M x Kp] * Bt[N x Kp]^T, fp32 accumulate.
// 128x128 block tile, BK=32, 4 waves (2x2), each wave 4x4 of 16x16x32 MFMA.
// blockIdx.z selects a K-slice of nk BK-iterations (split-K; z=0 when gridDim.z==1).
// EPI 0: tanh(+bias) -> dense fp16 Ch[row*ldc+col]
// EPI 1: raw -> SoA U planes: Ch[(col>>9)*M*512 + row*512 + (col&511)]
// EPI 3: raw fp32 partial -> Cf[z*M*NOUT + row*NOUT + col]   (split-K partial)
template <int EPI>
__global__ __launch_bounds__(256) void gemm_kernel(
    const _Float16* __restrict__ A, const _Float16* __restrict__ Bt,
    int Kp, int nk, int Nb,
    _Float16* __restrict__ Ch, float* __restrict__ Cf, int ldc,
    const float* __restrict__ bias)
{
    __shared__ __align__(16) _Float16 As[128][40];  // +8 pad, 16B-aligned rows
    __shared__ __align__(16) _Float16 Bs[128][40];

    const int tid  = threadIdx.x;
    const int m0   = blockIdx.x * 128;
    const int n0   = blockIdx.y * 128;
    const int koff = blockIdx.z * (nk << 5);   // K-slice origin
    const int wave = tid >> 6;
    const int lane = tid & 63;
    const int wr   = (wave >> 1) << 6;   // wave row offset (0/64)
    const int wc   = (wave & 1) << 6;    // wave col offset (0/64)
    const int lrow = lane & 15;
    const int lq   = lane >> 4;          // 0..3
    const int srow = tid >> 1;           // staging row 0..127
    const int scol = (tid & 1) << 4;     // staging col 0 or 16

    floatx4 acc[4][4];
    #pragma unroll
    for (int i = 0; i < 4; ++i)
        #pragma unroll
        for (int j = 0; j < 4; ++j)
            #pragma unroll
            for (int r = 0; r < 4; ++r) acc[i][j][r] = 0.f;

    const _Float16* aRow = A + (size_t)(m0 + srow) * Kp + koff;
    const int  brow   = n0 + srow;
    const _Float16* bRow = Bt + (size_t)brow * Kp + koff;
    const bool bvalid = (brow < Nb);

    for (int kc = 0; kc < nk; ++kc) {
        const int k0 = kc << 5;
        __syncthreads();
        #pragma unroll
        for (int s = 0; s < 2; ++s) {
            const int kk = k0 + scol + s * 8;
            half8 va = h8zero(), vb = h8zero();
            const bool kin = (koff + kk + 8 <= Kp);
            if (kin)           va = *(const half8*)(aRow + kk);
            if (kin && bvalid) vb = *(const half8*)(bRow + kk);
            *(half8*)(&As[srow][scol + s * 8]) = va;
            *(half8*)(&Bs[srow][scol + s * 8]) = vb;
        }
        __syncthreads();

        half8 af[4], bfr[4];
        #pragma unroll
        for (int i = 0; i < 4; ++i) af[i]  = *(const half8*)(&As[wr + i * 16 + lrow][lq * 8]);
        #pragma unroll
        for (int j = 0; j < 4; ++j) bfr[j] = *(const half8*)(&Bs[wc + j * 16 + lrow][lq * 8]);
        #pragma unroll
        for (int i = 0; i < 4; ++i)
            #pragma unroll
            for (int j = 0; j < 4; ++j)
                acc[i][j] = __builtin_amdgcn_mfma_f32_16x16x32_f16(af[i], bfr[j], acc[i][j], 0, 0, 0);
    }

    // Epilogue: C/D layout col=lane&15, row=quad*4+reg
    #pragma unroll
    for (int j = 0; j < 4; ++j) {
        const int col = n0 + wc + j * 16 + lrow;
        if (col >= Nb) continue;
        #pragma unroll
        for (int i = 0; i < 4; ++i) {
            #pragma unroll
            for (int r = 0; r < 4; ++r) {
                const int row = m0 + wr + i * 16 + lq * 4 + r;
                float v = acc[i][j][r];
                if constexpr (EPI == 0) {
                    float z = v + bias[col];
                    Ch[(size_t)row * ldc + col] = (_Float16)tanh_fast(z);
                } else if constexpr (EPI == 1) {
                    Ch[(size_t)(col >> 9) * ((size_t)M_ * 512) + (size_t)row * 512 + (col & 511)] = (_Float16)v;
                } else {
                    Cf[(size_t)blockIdx.z * M_ * NOUT + (size_t)row * NOUT + col] = v;
                }
            }
        }
    }
}

// ---------------------------------------------------------------------------
// Split-K reduction + sigmoid epilogue for the final GEMM.
__global__ __launch_bounds__(256) void reduce_out(
    const float* __restrict__ Cp, const float* __restrict__ bias,
    const float* __restrict__ aux, float* __restrict__ out)
{
    const size_t i = (size_t)blockIdx.x * 256 + threadIdx.x;
    if (i >= (size_t)M_ * NOUT) return;
    const int row = (int)(i / NOUT);
    const int col = (int)(i % NOUT);
    float s = Cp[i] + Cp[i + (size_t)M_ * NOUT] + Cp[i + 2 * (size_t)M_ * NOUT];
    out[i] = sigmoid_fast(s + bias[col]) * aux[(size_t)row * FEAT + 257 + col];
}

// ---------------------------------------------------------------------------
// Repack SoA U planes + X into packed Upk[m][h][4] = {xt, fp, rp, x} fp16.
// All loads are 8-B dense (half4 per 4 adjacent h), stores 16-B dense.
__global__ __launch_bounds__(256) void repack_u(
    const _Float16* __restrict__ U,   // 3 planes [M][512]
    const _Float16* __restrict__ X,   // [M][512] dense layer input
    _Float16* __restrict__ Upk)       // [M][512][4]
{
    const size_t i = (size_t)blockIdx.x * 256 + threadIdx.x;  // over M*128 4-h groups
    if (i >= (size_t)M_ * 128) return;
    const size_t base = i << 2;       // = m*512 + h (h multiple of 4)
    const half4 a = *(const half4*)(U + base);
    const half4 f = *(const half4*)(U + (size_t)M_ * 512 + base);
    const half4 r = *(const half4*)(U + 2 * (size_t)M_ * 512 + base);
    const half4 x = *(const half4*)(X + base);
    half8 lo, hi;
    lo[0] = a[0]; lo[1] = f[0]; lo[2] = r[0]; lo[3] = x[0];
    lo[4] = a[1]; lo[5] = f[1]; lo[6] = r[1]; lo[7] = x[1];
    hi[0] = a[2]; hi[1] = f[2]; hi[2] = r[2]; hi[3] = x[2];
    hi[4] = a[3]; hi[5] = f[3]; hi[6] = r[3]; hi[7] = x[3];
    *(half8*)(Upk + base * 4)     = lo;
    *(half8*)(Upk + base * 4 + 8) = hi;
}

// ---------------------------------------------------------------------------
// SRU scan over packed U: Upk[m][h][4] = {xt, fp, rp, x} as fp16.
// One coalesced 8B load per step per lane; depth-20 register ring (unrolled,
// compile-time indices -> stays in VGPRs, wide dwordx2 loads -> no d16 merge
// dependency) keeps 20 loads in flight. 1000 = 50 * 20, no tail.
__global__ __launch_bounds__(64) void sru_scan(
    const _Float16* __restrict__ Upk, _Float16* __restrict__ Xout,
    const float* __restrict__ v, const float* __restrict__ bg)
{
    const int gid = blockIdx.x * 64 + threadIdx.x;
    const int b = gid >> 9;
    const int h = gid & 511;
    const float vf = v[h],      vr = v[512 + h];
    const float bf = bg[h],     br = bg[512 + h];

    const _Float16* p = Upk + ((size_t)b * T_ * 512 + h) * 4;
    _Float16* ox = Xout + (size_t)b * T_ * 512 + h;

    half4 buf[20];
    #pragma unroll
    for (int j = 0; j < 20; ++j) buf[j] = *(const half4*)(p + (size_t)j * 2048);

    float c = 0.f;
    for (int t0 = 0; t0 < T_; t0 += 20) {
        #pragma unroll
        for (int j = 0; j < 20; ++j) {
            const int t = t0 + j;
            const half4 cur = buf[j];
            const int tn = t + 20;
            if (tn < T_) buf[j] = *(const half4*)(p + (size_t)tn * 2048);
            const float xt = (float)cur[0];
            const float fp = (float)cur[1];
            const float rp = (float)cur[2];
            const float x  = (float)cur[3];
            const float f  = sigmoid_fast(fp + vf * c + bf);
            const float r  = sigmoid_fast(rp + vr * c + br);
            const float cn = f * c + (1.0f - f) * xt;
            const float hO = r * cn + (1.0f - r) * x;
            ox[(size_t)t * 512] = (_Float16)hO;
            c = cn;
        }
    }
}

// ---------------------------------------------------------------------------
// Fused conv6x6(asym pad 3,2) + bias + tanh + maxpool3x3(pad 1).
// Weights are read with wave-uniform indices directly from global -> scalar
// loads into SGPRs (zero LDS weight traffic). cv kept in fp16 to halve LDS.
// Row loop rolled to bound register pressure (no scratch).
template <int JJ>
__device__ inline floatx4 window4(floatx4 a, floatx4 b, float r8) {
    floatx4 w;
    if constexpr (JJ == 0)      { w = a; }
    else if constexpr (JJ == 1) { w[0] = a[1]; w[1] = a[2]; w[2] = a[3]; w[3] = b[0]; }
    else if constexpr (JJ == 2) { w[0] = a[2]; w[1] = a[3]; w[2] = b[0]; w[3] = b[1]; }
    else if constexpr (JJ == 3) { w[0] = a[3]; w[1] = b[0]; w[2] = b[1]; w[3] = b[2]; }
    else if constexpr (JJ == 4) { w = b; }
    else                        { w[0] = b[1]; w[1] = b[2]; w[2] = b[3]; w[3] = r8; }
    return w;
}

#define CVW 76   // cv row width (halves)

__global__ __launch_bounds__(320) void conv_pool(
    const _Float16* __restrict__ X, const float* __restrict__ ck,
    const float* __restrict__ cb, _Float16* __restrict__ A3)
{
    __shared__ __align__(16) float    in_s[23][76];       // t0-4..t0+18, h0-4..h0+71 (fp32)
    __shared__ __align__(16) _Float16 cv[9][18][CVW];     // tanh(conv) fp16; -65504 = outside
    const int tid = threadIdx.x;
    int bi = blockIdx.x;
    const int th = bi & 7;  bi >>= 3;
    const int tt = bi % 63;
    const int b  = bi / 63;
    const int t0 = tt * 16, h0 = th * 64;

    for (int i = tid; i < 23 * 76; i += 320) {
        const int r = i / 76, cc = i % 76;
        const int gt = t0 - 4 + r, gh = h0 - 4 + cc;
        float val = 0.f;   // conv zero-padding
        if (gt >= 0 && gt < T_ && gh >= 0 && gh < H_)
            val = (float)X[((size_t)b * T_ + gt) * H_ + gh];
        in_s[r][cc] = val;
    }
    __syncthreads();

    // conv phase: 18 pt x 17 ph-groups = 306 tasks, one per thread
    if (tid < 306) {
        const int pt = tid / 17;        // conv row: ct = t0 - 1 + pt
        const int co = (tid % 17) * 4;  // conv col offset: ch = h0 - 1 + co + q
        const float* inb = &in_s[pt][co];

        const int ct = t0 - 1 + pt;
        const bool rok = (ct >= 0) && (ct < T_);
        const int chb = h0 - 1 + co;
        const bool ok0 = rok && (chb + 0 >= 0) && (chb + 0 < H_);
        const bool ok1 = rok && (chb + 1 >= 0) && (chb + 1 < H_);
        const bool ok2 = rok && (chb + 2 >= 0) && (chb + 2 < H_);
        const bool ok3 = rok && (chb + 3 >= 0) && (chb + 3 < H_);

        #define EMIT_K(K, VV)                                                  \
        {                                                                      \
            const floatx4 vz = (VV);                                           \
            const float bk = cb[K];                                            \
            half4 o;                                                           \
            o[0] = ok0 ? (_Float16)tanh_fast(vz[0] + bk) : (_Float16)(-65504.f); \
            o[1] = ok1 ? (_Float16)tanh_fast(vz[1] + bk) : (_Float16)(-65504.f); \
            o[2] = ok2 ? (_Float16)tanh_fast(vz[2] + bk) : (_Float16)(-65504.f); \
            o[3] = ok3 ? (_Float16)tanh_fast(vz[3] + bk) : (_Float16)(-65504.f); \
            *(half4*)(&cv[K][pt][co]) = o;                                     \
        }

        {   // pass 0: kernels 0..4 (weights via uniform scalar loads)
            floatx4 c0 = 0.f, c1 = 0.f, c2 = 0.f, c3 = 0.f, c4 = 0.f;
            #pragma unroll 1
            for (int ii = 0; ii < 6; ++ii) {
                const float* row = inb + ii * 76;
                const floatx4 ra = *(const floatx4*)(row);
                const floatx4 rb = *(const floatx4*)(row + 4);
                const float   r8 = row[8];
                const float* wt = ck + ii * 6;   // + k*36 + jj, wave-uniform
                #define TAP0(J)                                                \
                {                                                              \
                    const floatx4 win = window4<J>(ra, rb, r8);                \
                    c0 += wt[0 * 36 + (J)] * win;                              \
                    c1 += wt[1 * 36 + (J)] * win;                              \
                    c2 += wt[2 * 36 + (J)] * win;                              \
                    c3 += wt[3 * 36 + (J)] * win;                              \
                    c4 += wt[4 * 36 + (J)] * win;                              \
                }
                TAP0(0) TAP0(1) TAP0(2) TAP0(3) TAP0(4) TAP0(5)
                #undef TAP0
            }
            EMIT_K(0, c0) EMIT_K(1, c1) EMIT_K(2, c2) EMIT_K(3, c3) EMIT_K(4, c4)
        }
        {   // pass 1: kernels 5..8
            floatx4 c0 = 0.f, c1 = 0.f, c2 = 0.f, c3 = 0.f;
            #pragma unroll 1
            for (int ii = 0; ii < 6; ++ii) {
                const float* row = inb + ii * 76;
                const floatx4 ra = *(const floatx4*)(row);
                const floatx4 rb = *(const floatx4*)(row + 4);
                const float   r8 = row[8];
                const float* wt = ck + 5 * 36 + ii * 6;
                #define TAP1(J)                                                \
                {                                                              \
                    const floatx4 win = window4<J>(ra, rb, r8);                \
                    c0 += wt[0 * 36 + (J)] * win;                              \
                    c1 += wt[1 * 36 + (J)] * win;                              \
                    c2 += wt[2 * 36 + (J)] * win;                              \
                    c3 += wt[3 * 36 + (J)] * win;                              \
                }
                TAP1(0) TAP1(1) TAP1(2) TAP1(3) TAP1(4) TAP1(5)
                #undef TAP1
            }
            EMIT_K(5, c0) EMIT_K(6, c1) EMIT_K(7, c2) EMIT_K(8, c3)
        }
        #undef EMIT_K
    }
    __syncthreads();

    // pool phase: 16 pt x 16 ph-groups of 4 = 256 tasks
    if (tid < 256) {
        const int pt = tid >> 4;
        const int gt = t0 + pt;
        if (gt < T_) {
            const int ph = (tid & 15) * 4;
            _Float16* dst = A3 + ((size_t)b * T_ + gt) * KHID + (size_t)(h0 + ph) * KN_;
            #pragma unroll
            for (int k = 0; k < 9; ++k) {
                float q0 = -1e30f, q1 = -1e30f, q2 = -1e30f, q3 = -1e30f;
                #pragma unroll
                for (int dr = 0; dr < 3; ++dr) {
                    const _Float16* cr = &cv[k][pt + dr][ph];
                    const half4  a = *(const half4*)(cr);
                    const half2v bq = *(const half2v*)(cr + 4);
                    const float v0 = (float)a[0], v1 = (float)a[1], v2 = (float)a[2];
                    const float v3 = (float)a[3], v4 = (float)bq[0], v5 = (float)bq[1];
                    const float t01 = fmaxf(v1, v2);
                    const float t34 = fmaxf(v3, v4);
                    q0 = fmaxf(q0, fmaxf(v0, t01));
                    q1 = fmaxf(q1, fmaxf(t01, v3));
                    q2 = fmaxf(q2, fmaxf(v2, t34));
                    q3 = fmaxf(q3, fmaxf(t34, v5));
                }
                dst[0 * KN_ + k] = (_Float16)q0;
                dst[1 * KN_ + k] = (_Float16)q1;
                dst[2 * KN_ + k] = (_Float16)q2;
                dst[3 * KN_ + k] = (_Float16)q3;
            }
        }
    }
}

// ---------------------------------------------------------------------------
extern "C" void kernel_launch(void* const* d_in, const int* in_sizes, int n_in,
                              void* d_out, int out_size, void* d_ws, size_t ws_size,
                              hipStream_t stream) {
    const float* inputs = (const float*)d_in[0];
    const float* W_in   = (const float*)d_in[1];
    const float* b_in   = (const float*)d_in[2];
    const float* W_rnn  = (const float*)d_in[3];
    const float* v_rnn  = (const float*)d_in[4];
    const float* b_rnn  = (const float*)d_in[5];
    const float* conv_k = (const float*)d_in[6];
    const float* conv_b = (const float*)d_in[7];
    const float* W_out  = (const float*)d_in[8];
    const float* b_out  = (const float*)d_in[9];
    float* out = (float*)d_out;

    char* ws = (char*)d_ws;
    size_t off = 0;
    auto take = [&](size_t bytes) -> char* {
        off = (off + 255) & ~(size_t)255;
        char* p = ws + off;
        off += bytes;
        return p;
    };
    // W3T first so it survives; A1..X1 form a dead span at G3 time for Cp alias.
    _Float16* W3T  = (_Float16*)take((size_t)NOUT * KHID * 2);  // W_out[:,257:514]^T (live at G3)
    _Float16* A1   = (_Float16*)take((size_t)M_ * FEATP * 2);   // inputs fp16, padded (dead after G1)
    _Float16* W1T  = (_Float16*)take((size_t)H_ * FEATP * 2);   // W_in^T
    _Float16* W2T0 = (_Float16*)take((size_t)H3 * H_ * 2);      // W_rnn[0]^T
    _Float16* W2T1 = (_Float16*)take((size_t)H3 * H_ * 2);      // W_rnn[1]^T
    _Float16* X0   = (_Float16*)take((size_t)M_ * H_ * 2);      // tanh(G1); scan1 output (X2)
    _Float16* X1   = (_Float16*)take((size_t)M_ * H_ * 2);      // scan0 output
    _Float16* U    = (_Float16*)take(3 * (size_t)M_ * 512 * 2); // SoA U planes (xt,fp,rp)
    _Float16* A3   = (_Float16*)take((size_t)M_ * KHID * 2);    // pooled conv, (h*9+k) layout
    // Packed U aliases the head of A3 (dead until conv_pool runs; 65.5 MB < 147.5 MB):
    _Float16* Upk = A3;
    // Split-K partials alias the dead A1..X1 span (KSLICES*M*NOUT*4 = 49.4 MB < 61.6 MB span):
    float* Cp = (float*)A1;
    _Float16* X2 = X0;  // X0 dead after repack0 -> reuse for scan1 output

    // --- weight/input preprocessing (fp32 -> fp16, transpose to NxK) ---
    {
        size_t n = (size_t)M_ * FEATP;
        convert_inputs<<<dim3((unsigned)((n + 255) / 256)), 256, 0, stream>>>(inputs, A1);
    }
    transpose_w<<<dim3(25, 16), 256, 0, stream>>>(W_in, W1T, FEAT, H_, H_, 0, FEATP);
    transpose_w<<<dim3(16, 48), 256, 0, stream>>>(W_rnn, W2T0, H_, H3, H3, 0, H_);
    transpose_w<<<dim3(16, 48), 256, 0, stream>>>(W_rnn + (size_t)H_ * H3, W2T1, H_, H3, H3, 0, H_);
    transpose_w<<<dim3(144, 9), 256, 0, stream>>>(W_out, W3T, KHID, NOUT, FEAT, 257, KHID);

    const unsigned nrep = (unsigned)(((size_t)M_ * 128 + 255) / 256);

    // --- G1: X0 = tanh(inputs @ W_in + b_in) ---
    gemm_kernel<0><<<dim3(125, 4), 256, 0, stream>>>(A1, W1T, FEATP, 25, H_, X0, nullptr, H_, b_in);

    // --- SRU layer 0: U-GEMM (SoA) -> repack -> scan ---
    gemm_kernel<1><<<dim3(125, 12), 256, 0, stream>>>(X0, W2T0, H_, 16, H3, U, nullptr, 0, nullptr);
    repack_u<<<dim3(nrep), 256, 0, stream>>>(U, X0, Upk);
    sru_scan<<<dim3(128), 64, 0, stream>>>(Upk, X1, v_rnn, b_rnn);

    // --- SRU layer 1 ---
    gemm_kernel<1><<<dim3(125, 12), 256, 0, stream>>>(X1, W2T1, H_, 16, H3, U, nullptr, 0, nullptr);
    repack_u<<<dim3(nrep), 256, 0, stream>>>(U, X1, Upk);
    sru_scan<<<dim3(128), 64, 0, stream>>>(Upk, X2, v_rnn + 1024, b_rnn + 1024);

    // --- conv + tanh + maxpool fused, producing final-GEMM A matrix ---
    conv_pool<<<dim3(16 * 63 * 8), 320, 0, stream>>>(X2, conv_k, conv_b, A3);

    // --- G3 split-K: Cp[z] = A3 @ W3T (K-slice z), then reduce+sigmoid+mask ---
    gemm_kernel<3><<<dim3(125, 3, KSLICES), 256, 0, stream>>>(A3, W3T, KHID, 144 / KSLICES, NOUT, nullptr, Cp, 0, nullptr);
    {
        const unsigned nred = (unsigned)(((size_t)M_ * NOUT + 255) / 256);
        reduce_out<<<dim3(nred), 256, 0, stream>>>(Cp, b_out + 257, inputs, out);
    }
}